// Round 8
// baseline (209.128 us; speedup 1.0000x reference)
//
#include <hip/hip_runtime.h>

#define EPS 1e-8f

using short8 = __attribute__((ext_vector_type(8))) short;
using f32x16 = __attribute__((ext_vector_type(16))) float;
typedef unsigned short u16;

#define WAITV(N) asm volatile("s_waitcnt vmcnt(" #N ")" ::: "memory")
#define BARRIER() do { __builtin_amdgcn_s_barrier(); \
                       asm volatile("" ::: "memory"); } while (0)

__device__ __forceinline__ u16 f2bf(float f) {
    union { float f; unsigned u; } v; v.f = f;
    unsigned u = v.u;
    return (u16)((u + 0x7FFFu + ((u >> 16) & 1u)) >> 16);
}

__device__ __forceinline__ void g2l16(const void* gsrc, void* ldst) {
    __builtin_amdgcn_global_load_lds(
        (const __attribute__((address_space(1))) unsigned int*)gsrc,
        (__attribute__((address_space(3))) unsigned int*)ldst, 16, 0, 0);
}

// ---------------- kernel 1: style[b][i] = dot(w[b], affine_w[i]) + affine_b[i] + 1
__global__ void style_kernel(const float* __restrict__ w,        // [8][512]
                             const float* __restrict__ affine_w, // [256][512]
                             const float* __restrict__ affine_b, // [256]
                             float* __restrict__ style) {        // [8][256]
    int b = blockIdx.x;
    int i = threadIdx.x;
    __shared__ float wb[512];
    for (int z = threadIdx.x; z < 512; z += 256) wb[z] = w[b * 512 + z];
    __syncthreads();
    const float* aw = affine_w + i * 512;
    float acc = 0.f;
#pragma unroll 4
    for (int z = 0; z < 512; z += 4) {
        float4 a4 = *reinterpret_cast<const float4*>(aw + z);
        acc += a4.x * wb[z] + a4.y * wb[z + 1] + a4.z * wb[z + 2] + a4.w * wb[z + 3];
    }
    style[b * 256 + i] = acc + affine_b[i] + 1.0f;
}

// ---------------- kernel 2: modulate + demodulate, pack bf16 weights
// wgt layout: bf16 [b][t(9)][g(32)][o(256)][j(8)], ic = g*8 + j
__global__ void modw_kernel(const float* __restrict__ weight, // [256][256][3][3]
                            const float* __restrict__ style,  // [8][256]
                            u16* __restrict__ wgt) {
    int b = blockIdx.x >> 8;
    int o = blockIdx.x & 255;
    int ic = threadIdx.x; // 256 threads
    float s = style[b * 256 + ic];
    const float* wp = weight + (size_t)(o * 256 + ic) * 9;
    float m[9];
    float ss = 0.f;
#pragma unroll
    for (int t = 0; t < 9; ++t) { m[t] = wp[t] * s; ss += m[t] * m[t]; }
#pragma unroll
    for (int off = 32; off > 0; off >>= 1) ss += __shfl_down(ss, off);
    __shared__ float part[4];
    int lane = threadIdx.x & 63, wid = threadIdx.x >> 6;
    if (lane == 0) part[wid] = ss;
    __syncthreads();
    float denom = rsqrtf(part[0] + part[1] + part[2] + part[3] + EPS);
    int g = ic >> 3, j = ic & 7;
#pragma unroll
    for (int t = 0; t < 9; ++t) {
        size_t idx = ((((size_t)(b * 9 + t) * 32 + g) * 256 + o) << 3) + j;
        wgt[idx] = f2bf(m[t] * denom);
    }
}

// ---------------- kernel 3: x fp32 [8][256][128][128] -> bf16 xb [8][32][128][128][8]
__global__ __launch_bounds__(256) void xform_kernel(const float* __restrict__ x,
                                                    u16* __restrict__ xb) {
    int s = blockIdx.x * 256 + threadIdx.x; // (b,g,h,w)
    int w = s & 127, h = (s >> 7) & 127, g = (s >> 14) & 31, b = s >> 19;
    const float* xp = x + (((size_t)(b * 256 + g * 8) * 128 + h) * 128 + w);
    union { u16 u[8]; short8 v; } pk;
#pragma unroll
    for (int j = 0; j < 8; ++j) pk.u[j] = f2bf(xp[(size_t)j * 16384]);
    *reinterpret_cast<short8*>(&xb[(size_t)s * 8]) = pk.v;
}

// ---------------- kernel 4: implicit-GEMM conv, 32x32x16 MFMA, pair-tap barriers
// block = (b, ot, ht): 128 o x (2 rows x 128 w), 256 threads (4 waves), 2 blocks/CU.
// A: 5-deep LDS ring, prefetch DIST 3 (write at phase t hits slot of tap t-2;
// pair barriers at end of every odd phase always separate that read from the
// write -> race-free, unlike dist-4 which raced at even-phase writes).
// X: single LDS buf; reg-staged at t==5, ds_written at t==8 boundary.
// vmcnt never drains X early; barriers 6/chunk.
__global__ __launch_bounds__(256, 2) void conv_kernel(
    const u16* __restrict__ xb,  // [8][32][128][128][8] bf16
    const u16* __restrict__ wgt, // [8][9][32][256][8] bf16
    float* __restrict__ out) {   // [8][256][128][128]

    __shared__ __align__(16) u16 Xs[4][4][130][8]; // 33280 B [row][g][w130][j8]
    __shared__ __align__(16) u16 As[5][4][128][8]; // 40960 B [ring][g][o128][j8]
    __shared__ __align__(16) u16 trash[1024];      // chunk-0 OOB sink

    int bid = blockIdx.x;
    int swz = (bid & 7) * 128 + (bid >> 3); // grid 1024 = 8*128, bijective
    int ht = swz & 63, ot = (swz >> 6) & 1, b = swz >> 7;
    int h0 = ht * 2;

    int tid = threadIdx.x, lane = tid & 63, wid = tid >> 6;
    int wm = wid >> 1, wr = wid & 1; // wave -> (o half 64, row)
    int l31 = lane & 31, lh = lane >> 5;

    auto stageA = [&](int cc, int tt, int ring) { // 2 loads/wave, uniform
        const u16* wbase = wgt + ((size_t)(b * 9 + tt) * 32) * 2048;
#pragma unroll
        for (int k = 0; k < 2; ++k) {
            int seg = wid * 2 + k, g = seg >> 1, oh = seg & 1;
            const u16* src = wbase +
                ((size_t)(cc * 4 + g) * 256 + ot * 128 + oh * 64 + lane) * 8;
            g2l16(src, &As[ring][g][oh * 64][0]);
        }
    };

    // zero Xs (borders + OOB rows stay zero forever)
    {
        short8 z = {0, 0, 0, 0, 0, 0, 0, 0};
        short8* p0 = reinterpret_cast<short8*>(&Xs[0][0][0][0]);
        for (int i = tid; i < 2080; i += 256) p0[i] = z;
    }
    __syncthreads();

    // prologue: A taps 0..2 -> rings 0..2 (DIST 3) + X chunk 0 direct-to-LDS
    stageA(0, 0, 0); stageA(0, 1, 1); stageA(0, 2, 2);
    {
        int hr = h0 + wid - 1;
        bool oob = ((unsigned)hr >= 128u);
        int hc = oob ? 0 : hr;
#pragma unroll
        for (int k = 0; k < 8; ++k) {
            int g = k >> 1, half = k & 1;
            const u16* src = xb +
                ((((size_t)(b * 32 + g)) * 128 + hc) * 128 + half * 64 + lane) * 8;
            void* dst = oob ? (void*)trash : (void*)&Xs[wid][g][1 + half * 64][0];
            g2l16(src, dst);
        }
    }
    WAITV(0);
    BARRIER();

    f32x16 acc[2][4] = {};
    short8 xr[8];
    int rr = 0, rw = 3, cs = 0, ts = 3; // read ring; write ring; next stage (chunk,tap)

    auto doPhase = [&](int t, int ring) {
        int kh = t / 3, kw = t - kh * 3;
        short8 af[2][2], bx8[2][4];
#pragma unroll
        for (int kk = 0; kk < 2; ++kk)
#pragma unroll
            for (int mi = 0; mi < 2; ++mi)
                af[kk][mi] = *reinterpret_cast<const short8*>(
                    &As[ring][kk * 2 + lh][wm * 64 + mi * 32 + l31][0]);
#pragma unroll
        for (int kk = 0; kk < 2; ++kk)
#pragma unroll
            for (int ni = 0; ni < 4; ++ni)
                bx8[kk][ni] = *reinterpret_cast<const short8*>(
                    &Xs[wr + kh][kk * 2 + lh][ni * 32 + l31 + kw][0]);
        __builtin_amdgcn_s_setprio(1);
#pragma unroll
        for (int mi = 0; mi < 2; ++mi)
#pragma unroll
            for (int ni = 0; ni < 4; ++ni)
#pragma unroll
                for (int kk = 0; kk < 2; ++kk)
                    acc[mi][ni] = __builtin_amdgcn_mfma_f32_32x32x16_bf16(
                        af[kk][mi], bx8[kk][ni], acc[mi][ni], 0, 0, 0);
        __builtin_amdgcn_s_setprio(0);
    };

    int hr = h0 + wid - 1;
    bool hValid = ((unsigned)hr < 128u);
    int hc = hValid ? hr : 0;

    for (int c = 0; c < 7; ++c) {
#pragma unroll
        for (int t = 0; t < 9; ++t) {
            stageA(cs, ts, rw);
            if (++ts == 9) { ts = 0; ++cs; }
            if (t == 5) { // reg-stage X(c+1): 8 loads AFTER this phase's A issue
#pragma unroll
                for (int k = 0; k < 8; ++k) {
                    int g = k >> 1, half = k & 1;
                    xr[k] = *reinterpret_cast<const short8*>(xb +
                        ((((size_t)(b * 32 + (c + 1) * 4 + g)) * 128 + hc) * 128 +
                         half * 64 + lane) * 8);
                }
            }
            doPhase(t, rr);
            rr = (rr == 4) ? 0 : rr + 1;
            rw = (rw == 4) ? 0 : rw + 1;
            // pair-boundary sync (t = 1,3,5,7,8); FIFO ledger for DIST 3:
            if (t == 1 || t == 3) { WAITV(2);  BARRIER(); } // drain taps t+1,t+2; leave newest stage
            else if (t == 5)      { WAITV(10); BARRIER(); } // drain taps 6,7; leave t5-stage + X:8
            else if (t == 7)      { WAITV(12); BARRIER(); } // drain tap-8 stage; leave X + taps 0',1'
            else if (t == 8) {
                WAITV(2);  // drain X + taps 0',1'; leave tap-2' stage
                BARRIER(); // all waves done reading Xs chunk c
                if (hValid) {
#pragma unroll
                    for (int k = 0; k < 8; ++k) {
                        int g = k >> 1, half = k & 1;
                        *reinterpret_cast<short8*>(
                            &Xs[wid][g][1 + half * 64 + lane][0]) = xr[k];
                    }
                }
                asm volatile("s_waitcnt lgkmcnt(0)" ::: "memory");
                BARRIER(); // Xs(c+1) visible
            }
        }
    }
    // tail chunk c == 7: stages taps 66..71 at t=0..5; ramp down, pair boundaries
#pragma unroll
    for (int t = 0; t < 9; ++t) {
        if (t <= 5) {
            stageA(cs, ts, rw);
            if (++ts == 9) { ts = 0; ++cs; }
            rw = (rw == 4) ? 0 : rw + 1;
        }
        doPhase(t, rr);
        rr = (rr == 4) ? 0 : rr + 1;
        if (t == 1 || t == 3 || t == 5) { WAITV(2); BARRIER(); }
        else if (t == 7)                { WAITV(0); BARRIER(); } // tap 71 landed for t8
    }

    // epilogue: C/D 32x32 layout col=lane&31 (w), row=(reg&3)+8*(reg>>2)+4*(lane>>5) (o)
    int h = h0 + wr;
#pragma unroll
    for (int mi = 0; mi < 2; ++mi) {
        int ob = ot * 128 + wm * 64 + mi * 32 + 4 * lh;
#pragma unroll
        for (int ni = 0; ni < 4; ++ni) {
            int w_ = ni * 32 + l31;
#pragma unroll
            for (int reg = 0; reg < 16; ++reg) {
                int o = ob + (reg & 3) + 8 * (reg >> 2);
                out[(((size_t)(b * 256 + o) * 128 + h) * 128) + w_] = acc[mi][ni][reg];
            }
        }
    }
}

extern "C" void kernel_launch(void* const* d_in, const int* in_sizes, int n_in,
                              void* d_out, int out_size, void* d_ws, size_t ws_size,
                              hipStream_t stream) {
    const float* x        = (const float*)d_in[0];
    const float* w        = (const float*)d_in[1];
    const float* weight   = (const float*)d_in[2];
    const float* affine_w = (const float*)d_in[3];
    const float* affine_b = (const float*)d_in[4];
    float* out = (float*)d_out;

    float* style = (float*)d_ws;                                   // 8 KB
    u16* wgt = (u16*)((char*)d_ws + 8192);                         // 9.44 MB
    u16* xbuf = (u16*)((char*)d_ws + 8192 + 9437184);              // 64 MB

    xform_kernel<<<16384, 256, 0, stream>>>(x, xbuf);
    style_kernel<<<8, 256, 0, stream>>>(w, affine_w, affine_b, style);
    modw_kernel<<<2048, 256, 0, stream>>>(weight, style, wgt);
    conv_kernel<<<1024, 256, 0, stream>>>(xbuf, wgt, out);
}

// Round 9
// 196.280 us; speedup vs baseline: 1.0655x; 1.0655x over previous
//
#include <hip/hip_runtime.h>

#define EPS 1e-8f

using short8 = __attribute__((ext_vector_type(8))) short;
using f32x16 = __attribute__((ext_vector_type(16))) float;
typedef unsigned short u16;

#define WAITV(N) asm volatile("s_waitcnt vmcnt(" #N ")" ::: "memory")
#define BARRIER() do { __builtin_amdgcn_s_barrier(); \
                       asm volatile("" ::: "memory"); } while (0)

__device__ __forceinline__ u16 f2bf(float f) {
    union { float f; unsigned u; } v; v.f = f;
    unsigned u = v.u;
    return (u16)((u + 0x7FFFu + ((u >> 16) & 1u)) >> 16);
}

__device__ __forceinline__ void g2l16(const void* gsrc, void* ldst) {
    __builtin_amdgcn_global_load_lds(
        (const __attribute__((address_space(1))) unsigned int*)gsrc,
        (__attribute__((address_space(3))) unsigned int*)ldst, 16, 0, 0);
}

// ---------------- kernel 1: style[b][i] = dot(w[b], affine_w[i]) + affine_b[i] + 1
__global__ void style_kernel(const float* __restrict__ w,        // [8][512]
                             const float* __restrict__ affine_w, // [256][512]
                             const float* __restrict__ affine_b, // [256]
                             float* __restrict__ style) {        // [8][256]
    int b = blockIdx.x;
    int i = threadIdx.x;
    __shared__ float wb[512];
    for (int z = threadIdx.x; z < 512; z += 256) wb[z] = w[b * 512 + z];
    __syncthreads();
    const float* aw = affine_w + i * 512;
    float acc = 0.f;
#pragma unroll 4
    for (int z = 0; z < 512; z += 4) {
        float4 a4 = *reinterpret_cast<const float4*>(aw + z);
        acc += a4.x * wb[z] + a4.y * wb[z + 1] + a4.z * wb[z + 2] + a4.w * wb[z + 3];
    }
    style[b * 256 + i] = acc + affine_b[i] + 1.0f;
}

// ---------------- kernel 2: modulate + demodulate, pack bf16 weights
// wgt layout: bf16 [b][t(9)][g(32)][o(256)][j(8)], ic = g*8 + j
__global__ void modw_kernel(const float* __restrict__ weight, // [256][256][3][3]
                            const float* __restrict__ style,  // [8][256]
                            u16* __restrict__ wgt) {
    int b = blockIdx.x >> 8;
    int o = blockIdx.x & 255;
    int ic = threadIdx.x; // 256 threads
    float s = style[b * 256 + ic];
    const float* wp = weight + (size_t)(o * 256 + ic) * 9;
    float m[9];
    float ss = 0.f;
#pragma unroll
    for (int t = 0; t < 9; ++t) { m[t] = wp[t] * s; ss += m[t] * m[t]; }
#pragma unroll
    for (int off = 32; off > 0; off >>= 1) ss += __shfl_down(ss, off);
    __shared__ float part[4];
    int lane = threadIdx.x & 63, wid = threadIdx.x >> 6;
    if (lane == 0) part[wid] = ss;
    __syncthreads();
    float denom = rsqrtf(part[0] + part[1] + part[2] + part[3] + EPS);
    int g = ic >> 3, j = ic & 7;
#pragma unroll
    for (int t = 0; t < 9; ++t) {
        size_t idx = ((((size_t)(b * 9 + t) * 32 + g) * 256 + o) << 3) + j;
        wgt[idx] = f2bf(m[t] * denom);
    }
}

// ---------------- kernel 3: x fp32 [8][256][128][128] -> bf16 xb [8][32][128][128][8]
__global__ __launch_bounds__(256) void xform_kernel(const float* __restrict__ x,
                                                    u16* __restrict__ xb) {
    int s = blockIdx.x * 256 + threadIdx.x; // (b,g,h,w)
    int w = s & 127, h = (s >> 7) & 127, g = (s >> 14) & 31, b = s >> 19;
    const float* xp = x + (((size_t)(b * 256 + g * 8) * 128 + h) * 128 + w);
    union { u16 u[8]; short8 v; } pk;
#pragma unroll
    for (int j = 0; j < 8; ++j) pk.u[j] = f2bf(xp[(size_t)j * 16384]);
    *reinterpret_cast<short8*>(&xb[(size_t)s * 8]) = pk.v;
}

// ---------------- kernel 4: implicit-GEMM conv, 32x32x16 MFMA, barrier-free chunks
// block = (b, ot, ht): 128 o x (2 rows x 128 w), 256 threads (4 waves), 2 blocks/CU.
// A: global->VGPR per wave (coalesced 16B/lane, L2-resident), 1-phase prefetch
//    (afC/afN, copies renamed away under full unroll). NO A in LDS.
// X: LDS double-buffer; chunk c+1 staged via global_load_lds at t==0 into buf^1.
// Sync: ONE WAITV(4)+s_barrier per chunk (waves free-run 9 taps, de-phase and
// overlap each other's ds_reads with MFMAs). Issue order loadA->stageX keeps
// compiler-auto vmcnt waits for A from draining X early.
__global__ __launch_bounds__(256, 2) void conv_kernel(
    const u16* __restrict__ xb,  // [8][32][128][128][8] bf16
    const u16* __restrict__ wgt, // [8][9][32][256][8] bf16
    float* __restrict__ out) {   // [8][256][128][128]

    __shared__ __align__(16) u16 Xs[2][4][4][130][8]; // 66560 B [buf][row][g][w130][j8]
    __shared__ __align__(16) u16 trash[1024];         // OOB-row sink

    int bid = blockIdx.x;
    int swz = (bid & 7) * 128 + (bid >> 3); // grid 1024 = 8*128, bijective
    int ht = swz & 63, ot = (swz >> 6) & 1, b = swz >> 7;
    int h0 = ht * 2;

    int tid = threadIdx.x, lane = tid & 63, wid = tid >> 6;
    int wm = wid >> 1, wr = wid & 1; // wave -> (o half 64, row)
    int l31 = lane & 31, lh = lane >> 5;

    int hr = h0 + wid - 1;
    bool hValid = ((unsigned)hr < 128u);
    int hc = hValid ? hr : 0;

    // per-lane A base: (b, t=0, g=lh, o = ot*128 + wm*64 + l31)
    const u16* aBase = wgt + ((size_t)(b * 9) * 32 * 256 +
                              (size_t)(lh * 256 + ot * 128 + wm * 64 + l31)) * 8;

    auto loadA = [&](short8 dst[2][2], int c, int t) {
#pragma unroll
        for (int kk = 0; kk < 2; ++kk)
#pragma unroll
            for (int mi = 0; mi < 2; ++mi)
                dst[kk][mi] = *reinterpret_cast<const short8*>(
                    aBase + (size_t)(((t * 32) + c * 4 + kk * 2) * 256 + mi * 32) * 8);
    };
    auto stageX = [&](int c1, int bx) { // wave wid stages row wid: 8 x 1KB g2l16
#pragma unroll
        for (int k = 0; k < 8; ++k) {
            int g = k >> 1, half = k & 1;
            const u16* src = xb +
                ((((size_t)(b * 32 + c1 * 4 + g)) * 128 + hc) * 128 + half * 64 + lane) * 8;
            void* dst = hValid ? (void*)&Xs[bx][wid][g][1 + half * 64][0] : (void*)trash;
            g2l16(src, dst);
        }
    };

    // zero both X buffers (borders + OOB rows stay zero forever)
    {
        short8 z = {0, 0, 0, 0, 0, 0, 0, 0};
        short8* p0 = reinterpret_cast<short8*>(&Xs[0][0][0][0][0]);
        for (int i = tid; i < 4160; i += 256) p0[i] = z;
    }
    __syncthreads();

    short8 afC[2][2], afN[2][2];
    stageX(0, 0);          // X chunk 0 (oldest in FIFO)
    loadA(afC, 0, 0);      // afC in flight; compiler waits before first MFMA
    WAITV(4);              // drain X0; leave afC's 4 loads
    BARRIER();

    f32x16 acc[2][4] = {};

    for (int c = 0; c < 8; ++c) {
        int buf = c & 1;
#pragma unroll
        for (int t = 0; t < 9; ++t) {
            // prefetch A for next phase FIRST (so A-waits never drain X behind it)
            if (!(c == 7 && t == 8))
                loadA(afN, t < 8 ? c : c + 1, t < 8 ? t + 1 : 0);
            if (t == 0 && c < 7) stageX(c + 1, buf ^ 1);

            int kh = t / 3, kw = t - kh * 3;
            short8 bx8[2][4];
#pragma unroll
            for (int kk = 0; kk < 2; ++kk)
#pragma unroll
                for (int ni = 0; ni < 4; ++ni)
                    bx8[kk][ni] = *reinterpret_cast<const short8*>(
                        &Xs[buf][wr + kh][kk * 2 + lh][ni * 32 + l31 + kw][0]);
            __builtin_amdgcn_s_setprio(1);
#pragma unroll
            for (int mi = 0; mi < 2; ++mi)
#pragma unroll
                for (int ni = 0; ni < 4; ++ni)
#pragma unroll
                    for (int kk = 0; kk < 2; ++kk)
                        acc[mi][ni] = __builtin_amdgcn_mfma_f32_32x32x16_bf16(
                            afC[kk][mi], bx8[kk][ni], acc[mi][ni], 0, 0, 0);
            __builtin_amdgcn_s_setprio(0);
            // rotate prefetch (renamed away under full unroll)
#pragma unroll
            for (int kk = 0; kk < 2; ++kk)
#pragma unroll
                for (int mi = 0; mi < 2; ++mi)
                    afC[kk][mi] = afN[kk][mi];
        }
        // chunk boundary: X(c+1) (issued t0) must land for all waves; A(t8) stays in flight
        WAITV(4);
        BARRIER();
    }

    // epilogue: C/D 32x32 layout col=lane&31 (w), row=(reg&3)+8*(reg>>2)+4*(lane>>5) (o)
    int h = h0 + wr;
#pragma unroll
    for (int mi = 0; mi < 2; ++mi) {
        int ob = ot * 128 + wm * 64 + mi * 32 + 4 * lh;
#pragma unroll
        for (int ni = 0; ni < 4; ++ni) {
            int w_ = ni * 32 + l31;
#pragma unroll
            for (int reg = 0; reg < 16; ++reg) {
                int o = ob + (reg & 3) + 8 * (reg >> 2);
                out[(((size_t)(b * 256 + o) * 128 + h) * 128) + w_] = acc[mi][ni][reg];
            }
        }
    }
}

extern "C" void kernel_launch(void* const* d_in, const int* in_sizes, int n_in,
                              void* d_out, int out_size, void* d_ws, size_t ws_size,
                              hipStream_t stream) {
    const float* x        = (const float*)d_in[0];
    const float* w        = (const float*)d_in[1];
    const float* weight   = (const float*)d_in[2];
    const float* affine_w = (const float*)d_in[3];
    const float* affine_b = (const float*)d_in[4];
    float* out = (float*)d_out;

    float* style = (float*)d_ws;                                   // 8 KB
    u16* wgt = (u16*)((char*)d_ws + 8192);                         // 9.44 MB
    u16* xbuf = (u16*)((char*)d_ws + 8192 + 9437184);              // 64 MB

    xform_kernel<<<16384, 256, 0, stream>>>(x, xbuf);
    style_kernel<<<8, 256, 0, stream>>>(w, affine_w, affine_b, style);
    modw_kernel<<<2048, 256, 0, stream>>>(weight, style, wgt);
    conv_kernel<<<1024, 256, 0, stream>>>(xbuf, wgt, out);
}

// Round 10
// 192.459 us; speedup vs baseline: 1.0866x; 1.0199x over previous
//
#include <hip/hip_runtime.h>

#define EPS 1e-8f

using short8 = __attribute__((ext_vector_type(8))) short;
using f32x16 = __attribute__((ext_vector_type(16))) float;
typedef unsigned short u16;

#define WAITV(N) asm volatile("s_waitcnt vmcnt(" #N ")" ::: "memory")
#define BARRIER() do { __builtin_amdgcn_s_barrier(); \
                       asm volatile("" ::: "memory"); } while (0)

__device__ __forceinline__ u16 f2bf(float f) {
    union { float f; unsigned u; } v; v.f = f;
    unsigned u = v.u;
    return (u16)((u + 0x7FFFu + ((u >> 16) & 1u)) >> 16);
}

__device__ __forceinline__ void g2l16(const void* gsrc, void* ldst) {
    __builtin_amdgcn_global_load_lds(
        (const __attribute__((address_space(1))) unsigned int*)gsrc,
        (__attribute__((address_space(3))) unsigned int*)ldst, 16, 0, 0);
}

// ---------------- kernel 1: style[b][i] = dot(w[b], affine_w[i]) + affine_b[i] + 1
__global__ void style_kernel(const float* __restrict__ w,        // [8][512]
                             const float* __restrict__ affine_w, // [256][512]
                             const float* __restrict__ affine_b, // [256]
                             float* __restrict__ style) {        // [8][256]
    int b = blockIdx.x;
    int i = threadIdx.x;
    __shared__ float wb[512];
    for (int z = threadIdx.x; z < 512; z += 256) wb[z] = w[b * 512 + z];
    __syncthreads();
    const float* aw = affine_w + i * 512;
    float acc = 0.f;
#pragma unroll 4
    for (int z = 0; z < 512; z += 4) {
        float4 a4 = *reinterpret_cast<const float4*>(aw + z);
        acc += a4.x * wb[z] + a4.y * wb[z + 1] + a4.z * wb[z + 2] + a4.w * wb[z + 3];
    }
    style[b * 256 + i] = acc + affine_b[i] + 1.0f;
}

// ---------------- kernel 2: modulate + demodulate, pack bf16 weights
// wgt layout: bf16 [b][t(9)][g(32)][o(256)][j(8)], ic = g*8 + j
__global__ void modw_kernel(const float* __restrict__ weight, // [256][256][3][3]
                            const float* __restrict__ style,  // [8][256]
                            u16* __restrict__ wgt) {
    int b = blockIdx.x >> 8;
    int o = blockIdx.x & 255;
    int ic = threadIdx.x; // 256 threads
    float s = style[b * 256 + ic];
    const float* wp = weight + (size_t)(o * 256 + ic) * 9;
    float m[9];
    float ss = 0.f;
#pragma unroll
    for (int t = 0; t < 9; ++t) { m[t] = wp[t] * s; ss += m[t] * m[t]; }
#pragma unroll
    for (int off = 32; off > 0; off >>= 1) ss += __shfl_down(ss, off);
    __shared__ float part[4];
    int lane = threadIdx.x & 63, wid = threadIdx.x >> 6;
    if (lane == 0) part[wid] = ss;
    __syncthreads();
    float denom = rsqrtf(part[0] + part[1] + part[2] + part[3] + EPS);
    int g = ic >> 3, j = ic & 7;
#pragma unroll
    for (int t = 0; t < 9; ++t) {
        size_t idx = ((((size_t)(b * 9 + t) * 32 + g) * 256 + o) << 3) + j;
        wgt[idx] = f2bf(m[t] * denom);
    }
}

// ---------------- kernel 3: x fp32 [8][256][128][128] -> bf16 xb [8][32][128][128][8]
__global__ __launch_bounds__(256) void xform_kernel(const float* __restrict__ x,
                                                    u16* __restrict__ xb) {
    int s = blockIdx.x * 256 + threadIdx.x; // (b,g,h,w)
    int w = s & 127, h = (s >> 7) & 127, g = (s >> 14) & 31, b = s >> 19;
    const float* xp = x + (((size_t)(b * 256 + g * 8) * 128 + h) * 128 + w);
    union { u16 u[8]; short8 v; } pk;
#pragma unroll
    for (int j = 0; j < 8; ++j) pk.u[j] = f2bf(xp[(size_t)j * 16384]);
    *reinterpret_cast<short8*>(&xb[(size_t)s * 8]) = pk.v;
}

// ---------------- kernel 4: implicit-GEMM conv, 32x32x16 MFMA, half-tap pipeline
// block = (b, ot, ht): 128 o x (2 rows x 128 w), 256 threads (4 waves), 2 blocks/CU.
// A: global->VGPR per wave (L2-resident), 1-tap prefetch afC/afN.
// X: LDS double-buffer; chunk c+1 staged via global_load_lds at hp==1 (AFTER
//    that tap's loadA, so A-waits never drain X in the vmcnt FIFO).
// Inner chunk: 18 half-phases, bx ping-pong (2x4 frags, register-neutral vs R9):
//    each half issues the NEXT half's 4 ds_reads before its 8-MFMA cluster ->
//    LDS latency hides under MFMA per wave. One WAITV(4)+barrier per chunk.
__global__ __launch_bounds__(256, 2) void conv_kernel(
    const u16* __restrict__ xb,  // [8][32][128][128][8] bf16
    const u16* __restrict__ wgt, // [8][9][32][256][8] bf16
    float* __restrict__ out) {   // [8][256][128][128]

    __shared__ __align__(16) u16 Xs[2][4][4][130][8]; // 66560 B [buf][row][g][w130][j8]
    __shared__ __align__(16) u16 trash[1024];         // OOB-row sink

    int bid = blockIdx.x;
    int swz = (bid & 7) * 128 + (bid >> 3); // grid 1024 = 8*128, bijective
    int ht = swz & 63, ot = (swz >> 6) & 1, b = swz >> 7;
    int h0 = ht * 2;

    int tid = threadIdx.x, lane = tid & 63, wid = tid >> 6;
    int wm = wid >> 1, wr = wid & 1; // wave -> (o half 64, row)
    int l31 = lane & 31, lh = lane >> 5;

    int hr = h0 + wid - 1;
    bool hValid = ((unsigned)hr < 128u);
    int hc = hValid ? hr : 0;

    // per-lane A base: (b, t=0, g=lh, o = ot*128 + wm*64 + l31)
    const u16* aBase = wgt + ((size_t)(b * 9) * 32 * 256 +
                              (size_t)(lh * 256 + ot * 128 + wm * 64 + l31)) * 8;

    auto loadA = [&](short8 dst[2][2], int c, int t) {
#pragma unroll
        for (int kk = 0; kk < 2; ++kk)
#pragma unroll
            for (int mi = 0; mi < 2; ++mi)
                dst[kk][mi] = *reinterpret_cast<const short8*>(
                    aBase + (size_t)(((t * 32) + c * 4 + kk * 2) * 256 + mi * 32) * 8);
    };
    auto stageX = [&](int c1, int bx) { // wave wid stages row wid: 8 x 1KB g2l16
#pragma unroll
        for (int k = 0; k < 8; ++k) {
            int g = k >> 1, half = k & 1;
            const u16* src = xb +
                ((((size_t)(b * 32 + c1 * 4 + g)) * 128 + hc) * 128 + half * 64 + lane) * 8;
            void* dst = hValid ? (void*)&Xs[bx][wid][g][1 + half * 64][0] : (void*)trash;
            g2l16(src, dst);
        }
    };

    // zero both X buffers (borders + OOB rows stay zero forever)
    {
        short8 z = {0, 0, 0, 0, 0, 0, 0, 0};
        short8* p0 = reinterpret_cast<short8*>(&Xs[0][0][0][0][0]);
        for (int i = tid; i < 4160; i += 256) p0[i] = z;
    }
    __syncthreads();

    short8 afC[2][2], afN[2][2];
    stageX(0, 0);          // X chunk 0 (oldest in FIFO)
    loadA(afC, 0, 0);      // afC in flight; compiler waits before first MFMA
    WAITV(4);              // drain X0; leave afC's 4 loads
    BARRIER();

    f32x16 acc[2][4] = {};
    short8 bxb[2][4];      // half-tap ping-pong (statically indexed under unroll)

    for (int c = 0; c < 8; ++c) {
        int buf = c & 1;
        // pre-read first half (t=0, kk=0, kh=0, kw=0)
#pragma unroll
        for (int ni = 0; ni < 4; ++ni)
            bxb[0][ni] = *reinterpret_cast<const short8*>(
                &Xs[buf][wr][lh][ni * 32 + l31][0]);
#pragma unroll
        for (int hp = 0; hp < 18; ++hp) {
            int t = hp >> 1, kk = hp & 1;
            // 1) prefetch next half's B frags (before this half's MFMA cluster)
            if (hp < 17) {
                int hp2 = hp + 1, t2 = hp2 >> 1, kk2 = hp2 & 1;
                int kh2 = t2 / 3, kw2 = t2 - kh2 * 3;
#pragma unroll
                for (int ni = 0; ni < 4; ++ni)
                    bxb[hp2 & 1][ni] = *reinterpret_cast<const short8*>(
                        &Xs[buf][wr + kh2][kk2 * 2 + lh][ni * 32 + l31 + kw2][0]);
            }
            // 2) A prefetch for next tap (kk==1), THEN X stage (hp==1) so the
            //    vmcnt FIFO keeps A-waits from draining X.
            if (kk == 1 && !(c == 7 && t == 8))
                loadA(afN, t < 8 ? c : c + 1, t < 8 ? t + 1 : 0);
            if (hp == 1 && c < 7) stageX(c + 1, buf ^ 1);

            // 3) MFMA cluster on current half
            __builtin_amdgcn_s_setprio(1);
#pragma unroll
            for (int mi = 0; mi < 2; ++mi)
#pragma unroll
                for (int ni = 0; ni < 4; ++ni)
                    acc[mi][ni] = __builtin_amdgcn_mfma_f32_32x32x16_bf16(
                        afC[kk][mi], bxb[hp & 1][ni], acc[mi][ni], 0, 0, 0);
            __builtin_amdgcn_s_setprio(0);

            if (kk == 1 && !(c == 7 && t == 8)) {
#pragma unroll
                for (int k2 = 0; k2 < 2; ++k2)
#pragma unroll
                    for (int mi = 0; mi < 2; ++mi)
                        afC[k2][mi] = afN[k2][mi];
            }
        }
        // chunk boundary: drain X(c+1) (+ older A's); leave newest afN in flight
        if (c < 7) { WAITV(4); BARRIER(); }
    }

    // epilogue: C/D 32x32 layout col=lane&31 (w), row=(reg&3)+8*(reg>>2)+4*(lane>>5) (o)
    int h = h0 + wr;
#pragma unroll
    for (int mi = 0; mi < 2; ++mi) {
        int ob = ot * 128 + wm * 64 + mi * 32 + 4 * lh;
#pragma unroll
        for (int ni = 0; ni < 4; ++ni) {
            int w_ = ni * 32 + l31;
#pragma unroll
            for (int reg = 0; reg < 16; ++reg) {
                int o = ob + (reg & 3) + 8 * (reg >> 2);
                out[(((size_t)(b * 256 + o) * 128 + h) * 128) + w_] = acc[mi][ni][reg];
            }
        }
    }
}

extern "C" void kernel_launch(void* const* d_in, const int* in_sizes, int n_in,
                              void* d_out, int out_size, void* d_ws, size_t ws_size,
                              hipStream_t stream) {
    const float* x        = (const float*)d_in[0];
    const float* w        = (const float*)d_in[1];
    const float* weight   = (const float*)d_in[2];
    const float* affine_w = (const float*)d_in[3];
    const float* affine_b = (const float*)d_in[4];
    float* out = (float*)d_out;

    float* style = (float*)d_ws;                                   // 8 KB
    u16* wgt = (u16*)((char*)d_ws + 8192);                         // 9.44 MB
    u16* xbuf = (u16*)((char*)d_ws + 8192 + 9437184);              // 64 MB

    xform_kernel<<<16384, 256, 0, stream>>>(x, xbuf);
    style_kernel<<<8, 256, 0, stream>>>(w, affine_w, affine_b, style);
    modw_kernel<<<2048, 256, 0, stream>>>(weight, style, wgt);
    conv_kernel<<<1024, 256, 0, stream>>>(xbuf, wgt, out);
}